// Round 15
// baseline (399.207 us; speedup 1.0000x reference)
//
#include <hip/hip_runtime.h>
#include <hip/hip_fp16.h>

#define NB   16       // batches
#define NN   10000    // nodes per batch
#define NE   160000   // edges per batch
#define NODES (NB*NN) // 160000 total nodes
#define IN_F 19
#define HF   64
#define OUTF 32
#define LN_EPS 1e-5f
#define RANGE 625     // dst nodes per bucket (16 buckets/batch)
#define NCHUNK 32     // edge chunks per batch in bucket_kernel
#define CHSZ (NE/NCHUNK)   // 5000 edges per chunk
#define BCAP 16384    // bucket capacity (entries); mean 10000, sigma ~97

// R28: R27's enc was latency-starved: 625 blocks = 2500 waves = 2.4/SIMD
// (Occupancy 20-23%, VALUBusy 23-29%), and compiler capped VGPR at 84 ->
// residual spill (WRITE_SIZE 27.3MB vs 20.5 ideal). Fix: gemm64 geometry --
// 2 threads/node (wave = 64 nodes x one 32-col half, half pinned uniform),
// h[64] computed redundantly per half (+1216 cheap fma), grid 1250 blocks =
// 5000 waves; __launch_bounds__(256,2) lifts VGPR cap to 256 -> no spill.
// Per-column FP chain order source-identical to R27. agg/conv/out/CSR
// byte-identical to R27 (conv frozen; agg R21-form+XCD map).
// Pre-commit: absmax >= 0.065 or total > 392 -> revert to R27 (392.0).

__device__ inline unsigned pk_f16(float a, float b) {
    __half2 h = __float22half2_rn(float2{a, b});
    return *(unsigned*)&h;
}
__device__ inline float2 upk_f16(unsigned u) {
    __half2 h = *(__half2*)&u;
    return __half22float2(h);
}

typedef _Float16 f16x8 __attribute__((ext_vector_type(8)));
typedef float    f32x4 __attribute__((ext_vector_type(4)));

// ---------------- enc (fused, 2 thr/node): xh = relu(nf@W1+b1)@W2 + b2 ----------------
__global__ __launch_bounds__(256, 2) void enc_kernel(
    const float* __restrict__ nf,
    const float* __restrict__ w1, const float* __restrict__ b1,
    const float* __restrict__ w2, const float* __restrict__ b2,
    __half* __restrict__ xh)
{
    int lane = threadIdx.x & 63;
    int waveid = threadIdx.x >> 6;               // 0..3
    int half = __builtin_amdgcn_readfirstlane(waveid & 1);   // pin uniformity
    int nib = (waveid >> 1) * 64 + lane;         // node-in-block 0..127
    int node = blockIdx.x * 128 + nib;           // 1250 blocks * 128 = 160000

    const float* p = nf + (size_t)node * IN_F;
    float a[IN_F];
#pragma unroll
    for (int k = 0; k < IN_F; ++k) a[k] = p[k];

    float h[HF];
#pragma unroll
    for (int j = 0; j < HF; ++j) h[j] = b1[j];
#pragma unroll
    for (int k = 0; k < IN_F; ++k) {
        float ak = a[k];
        const float* wr = w1 + k * HF;           // wave-uniform -> s_load
#pragma unroll
        for (int j = 0; j < HF; ++j) h[j] = fmaf(ak, wr[j], h[j]);
    }
#pragma unroll
    for (int j = 0; j < HF; ++j) h[j] = fmaxf(h[j], 0.f);

    // second GEMM: this thread's 32-col half; k fully unrolled (h[k] static)
    float acc[32];
    const float* b2h = b2 + half * 32;
#pragma unroll
    for (int j = 0; j < 32; ++j) acc[j] = b2h[j];
    const float* wbase = w2 + half * 32;         // uniform offset
#pragma unroll
    for (int k = 0; k < HF; ++k) {
        const float* wr = wbase + k * HF;        // uniform -> s_load
        float ak = h[k];
#pragma unroll
        for (int j = 0; j < 32; ++j) acc[j] = fmaf(ak, wr[j], acc[j]);
    }

    uint4* hdst = (uint4*)(xh + (size_t)node * HF + half * 32);
#pragma unroll
    for (int q = 0; q < 4; ++q) {
        uint4 u;
        u.x = pk_f16(acc[8*q+0], acc[8*q+1]);
        u.y = pk_f16(acc[8*q+2], acc[8*q+3]);
        u.z = pk_f16(acc[8*q+4], acc[8*q+5]);
        u.w = pk_f16(acc[8*q+6], acc[8*q+7]);
        hdst[q] = u;
    }
}

// ---------------- bucket: bin edge chunks into per-(batch,range) buckets ----------------
__global__ __launch_bounds__(256) void bucket_kernel(const int* __restrict__ ei,
                                                     int* __restrict__ gcur,
                                                     unsigned* __restrict__ bkt)
{
    __shared__ int lcnt[16];
    __shared__ int lcur[16];
    __shared__ int gbase[16];
    int b = blockIdx.x >> 5;                     // NCHUNK=32 chunks per batch
    int chunk = blockIdx.x & 31;
    int t = threadIdx.x;
    if (t < 16) { lcnt[t] = 0; lcur[t] = 0; }
    __syncthreads();

    const int* srcp = ei + (size_t)b * 2 * NE + chunk * CHSZ;
    const int* dstp = srcp + NE;

    for (int e = t; e < CHSZ; e += 256)
        atomicAdd(&lcnt[(unsigned)dstp[e] / RANGE], 1);
    __syncthreads();
    if (t < 16) gbase[t] = atomicAdd(&gcur[b * 16 + t], lcnt[t]);
    __syncthreads();

    for (int e = t; e < CHSZ; e += 256) {
        int d = dstp[e];                          // L1-hot (2nd pass)
        int s = srcp[e];
        int j = (unsigned)d / RANGE;
        int ld = d - j * RANGE;
        int pos = gbase[j] + atomicAdd(&lcur[j], 1);
        if (pos < BCAP)
            bkt[(size_t)(b * 16 + j) * BCAP + pos] = (unsigned)s | ((unsigned)ld << 16);
    }
}

// ---------------- count2: per-bucket histogram -> cnt ----------------
__global__ __launch_bounds__(512) void count2_kernel(const unsigned* __restrict__ bkt,
                                                     const int* __restrict__ gcur,
                                                     int* __restrict__ cnt)
{
    __shared__ int lcnt[RANGE];
    int bid = blockIdx.x;                        // b*16 + j
    int b = bid >> 4, j = bid & 15;
    int t = threadIdx.x;
    for (int i = t; i < RANGE; i += 512) lcnt[i] = 0;
    __syncthreads();
    int n = min(gcur[bid], BCAP);
    const unsigned* bp = bkt + (size_t)bid * BCAP;
    for (int e = t; e < n; e += 512) atomicAdd(&lcnt[bp[e] >> 16], 1);
    __syncthreads();
    int base = b * NN + j * RANGE;
    for (int i = t; i < RANGE; i += 512) cnt[base + i] = lcnt[i];
}

// ---------------- scan: per-batch exclusive prefix over cnt ----------------
__global__ __launch_bounds__(256) void scan_kernel(const int* __restrict__ cnt, int* __restrict__ off)
{
    __shared__ int sdata[256];
    int b = blockIdx.x, t = threadIdx.x;
    const int CH = 40;                          // 256*40 = 10240 >= NN
    int lo = t * CH, hi = min(lo + CH, NN);
    int s = 0;
    for (int i = lo; i < hi; ++i) s += cnt[b * NN + i];
    sdata[t] = s;
    __syncthreads();
    for (int ofs = 1; ofs < 256; ofs <<= 1) {
        int v = (t >= ofs) ? sdata[t - ofs] : 0;
        __syncthreads();
        sdata[t] += v;
        __syncthreads();
    }
    int run = (t > 0) ? sdata[t - 1] : 0;       // exclusive prefix
    for (int i = lo; i < hi; ++i) { off[b * NN + i] = run; run += cnt[b * NN + i]; }
}

// ---------------- fill2: per-bucket fill of the block-owned CSR segment ----------------
__global__ __launch_bounds__(512) void fill2_kernel(const unsigned* __restrict__ bkt,
                                                    const int* __restrict__ gcur,
                                                    const int* __restrict__ off,
                                                    int* __restrict__ csr)
{
    __shared__ int lcur[RANGE];
    int bid = blockIdx.x;                        // b*16 + j
    int b = bid >> 4, j = bid & 15;
    int t = threadIdx.x;
    for (int i = t; i < RANGE; i += 512) lcur[i] = 0;
    __syncthreads();
    int n = min(gcur[bid], BCAP);
    const unsigned* bp = bkt + (size_t)bid * BCAP;
    const int* offb = off + b * NN + j * RANGE;
    int* csrb = csr + (size_t)b * NE;
    for (int e = t; e < n; e += 512) {
        unsigned u = bp[e];
        int ld = u >> 16;
        int pos = offb[ld] + atomicAdd(&lcur[ld], 1);
        csrb[pos] = (int)(u & 0xffffu);          // block-exclusive ~40KB segment
    }
}

// ---------------- mean aggregation (R25 verbatim): R21 FP code, XCD-pinned map ----
__global__ __launch_bounds__(256) void agg_kernel(const __half* __restrict__ xh,
                                                  const int* __restrict__ cnt,
                                                  const int* __restrict__ off,
                                                  const int* __restrict__ csr,
                                                  __half* __restrict__ aggh)
{
    int bid = blockIdx.x;
    int x = bid & 7;                                // presumed XCD slot
    int r = bid >> 3;                               // 0..4999
    int b = x + ((r & 1) << 3);                     // batch: XCD x -> {x, x+8}
    int chunk = r >> 1;                             // 0..2499  (bijective map)
    int wid = threadIdx.x >> 6;                     // 4 waves = 4 nodes per block
    int n = chunk * 4 + wid;                        // 0..9999
    int w = b * NN + n;
    w = __builtin_amdgcn_readfirstlane(w);          // wave-uniform -> scalar loads
    int lane = threadIdx.x & 63;
    unsigned g  = (unsigned)(lane >> 5);            // edge group 0/1
    unsigned cl = (unsigned)(lane & 31);            // uint index = 2 channels
    int c = cnt[w];
    int o = off[w];
    const int* row = csr + (size_t)b * NE + o;      // uniform -> s_load
    const unsigned* xbu = (const unsigned*)(xh + (size_t)b * NN * HF);
    float a0 = 0.f, a1 = 0.f;
    int t = 0;
    for (; t + 16 <= c; t += 16) {                  // 16 edges/iter, 8 gathers in flight
        int i0 = row[t],    i1 = row[t+1],  i2 = row[t+2],  i3 = row[t+3];
        int i4 = row[t+4],  i5 = row[t+5],  i6 = row[t+6],  i7 = row[t+7];
        int i8 = row[t+8],  i9 = row[t+9],  iA = row[t+10], iB = row[t+11];
        int iC = row[t+12], iD = row[t+13], iE = row[t+14], iF = row[t+15];
        unsigned j0 = (unsigned)(g ? i1 : i0);
        unsigned j1 = (unsigned)(g ? i3 : i2);
        unsigned j2 = (unsigned)(g ? i5 : i4);
        unsigned j3 = (unsigned)(g ? i7 : i6);
        unsigned j4 = (unsigned)(g ? i9 : i8);
        unsigned j5 = (unsigned)(g ? iB : iA);
        unsigned j6 = (unsigned)(g ? iD : iC);
        unsigned j7 = (unsigned)(g ? iF : iE);
        unsigned u0 = xbu[j0 * 32u + cl];
        unsigned u1 = xbu[j1 * 32u + cl];
        unsigned u2 = xbu[j2 * 32u + cl];
        unsigned u3 = xbu[j3 * 32u + cl];
        unsigned u4 = xbu[j4 * 32u + cl];
        unsigned u5 = xbu[j5 * 32u + cl];
        unsigned u6 = xbu[j6 * 32u + cl];
        unsigned u7 = xbu[j7 * 32u + cl];
        float2 f0 = upk_f16(u0), f1 = upk_f16(u1), f2 = upk_f16(u2), f3 = upk_f16(u3);
        float2 f4 = upk_f16(u4), f5 = upk_f16(u5), f6 = upk_f16(u6), f7 = upk_f16(u7);
        a0 += f0.x; a1 += f0.y;
        a0 += f1.x; a1 += f1.y;
        a0 += f2.x; a1 += f2.y;
        a0 += f3.x; a1 += f3.y;
        a0 += f4.x; a1 += f4.y;
        a0 += f5.x; a1 += f5.y;
        a0 += f6.x; a1 += f6.y;
        a0 += f7.x; a1 += f7.y;
    }
    if (t + 8 <= c) {                               // one R14 8-edge body
        int i0 = row[t],   i1 = row[t+1], i2 = row[t+2], i3 = row[t+3];
        int i4 = row[t+4], i5 = row[t+5], i6 = row[t+6], i7 = row[t+7];
        unsigned j0 = (unsigned)(g ? i1 : i0);
        unsigned j1 = (unsigned)(g ? i3 : i2);
        unsigned j2 = (unsigned)(g ? i5 : i4);
        unsigned j3 = (unsigned)(g ? i7 : i6);
        unsigned u0 = xbu[j0 * 32u + cl];
        unsigned u1 = xbu[j1 * 32u + cl];
        unsigned u2 = xbu[j2 * 32u + cl];
        unsigned u3 = xbu[j3 * 32u + cl];
        float2 f0 = upk_f16(u0), f1 = upk_f16(u1), f2 = upk_f16(u2), f3 = upk_f16(u3);
        a0 += f0.x; a1 += f0.y;
        a0 += f1.x; a1 += f1.y;
        a0 += f2.x; a1 += f2.y;
        a0 += f3.x; a1 += f3.y;
        t += 8;
    }
    for (; t + 2 <= c; t += 2) {
        int i0 = row[t], i1 = row[t+1];
        unsigned j = (unsigned)(g ? i1 : i0);
        float2 f = upk_f16(xbu[j * 32u + cl]);
        a0 += f.x; a1 += f.y;
    }
    if (t < c && g == 0) {                          // odd leftover: group 0 only
        float2 f = upk_f16(xbu[(unsigned)row[t] * 32u + cl]);
        a0 += f.x; a1 += f.y;
    }
    a0 += __shfl_xor(a0, 32, 64);                   // cross-group reduce
    a1 += __shfl_xor(a1, 32, 64);
    float inv = (c > 0) ? 1.f / (float)c : 0.f;
    unsigned pk = pk_f16(a0 * inv, a1 * inv);
    if (g == 0) ((unsigned*)aggh)[(size_t)w * 32 + cl] = pk;
}

// ---------------- conv (MFMA, R21/R14 form, FROZEN): 64 nodes/block ----------------
__global__ __launch_bounds__(256) void conv_kernel(
    __half* __restrict__ xh, const __half* __restrict__ aggh,
    const float* __restrict__ W, const float* __restrict__ bias,
    const float* __restrict__ g, const float* __restrict__ beta)
{
    __shared__ __half Wt[64][136];    // Wt[col][k] = f16(W[k][col]); stride 136: 16B-aligned
    __shared__ float s_out[64][68];   // fp32 matmul result; stride 68: 16B-aligned

    int t = threadIdx.x;

    // ---- stage W^T as f16 into LDS (coalesced global reads) ----
    {
        int c  = t & 63;
        int kb = (t >> 6) * 32;                   // wave w covers k rows kb..kb+31
#pragma unroll
        for (int k = 0; k < 32; k += 2) {
            float w0 = W[(size_t)(kb + k)     * HF + c];
            float w1 = W[(size_t)(kb + k + 1) * HF + c];
            *(__half2*)&Wt[c][kb + k] = __float22half2_rn(float2{w0, w1});
        }
    }
    __syncthreads();

    // ---- per-wave 16x64 output tile via 16 MFMAs ----
    int l     = t & 63;
    int wv    = t >> 6;                           // wave 0..3 -> node rows wv*16..wv*16+15
    int arow16 = l & 15;                          // A-frag row within tile
    int ks    = (l >> 4) * 8;                     // A/B-frag k-slot base: 0,8,16,24
    int node  = blockIdx.x * 64 + wv * 16 + arow16;

    const __half* xrow = xh   + (size_t)node * HF;
    const __half* grow = aggh + (size_t)node * HF;
    f16x8 a0 = *(const f16x8*)(xrow + ks);        // k =   0+ks..   (x half, W rows 0..63)
    f16x8 a1 = *(const f16x8*)(xrow + 32 + ks);   // k =  32+ks..
    f16x8 a2 = *(const f16x8*)(grow + ks);        // k =  64+ks..   (agg half, W rows 64..127)
    f16x8 a3 = *(const f16x8*)(grow + 32 + ks);   // k =  96+ks..

    int orow = wv * 16 + (l >> 4) * 4;            // D rows this lane holds (reg j -> orow+j)
#pragma unroll
    for (int ct = 0; ct < 4; ++ct) {              // 4 column tiles of 16
        int col = (l & 15) + ct * 16;
        f16x8 b0 = *(const f16x8*)&Wt[col][ks];
        f16x8 b1 = *(const f16x8*)&Wt[col][32 + ks];
        f16x8 b2 = *(const f16x8*)&Wt[col][64 + ks];
        f16x8 b3 = *(const f16x8*)&Wt[col][96 + ks];
        f32x4 acc = {0.f, 0.f, 0.f, 0.f};
        acc = __builtin_amdgcn_mfma_f32_16x16x32_f16(a0, b0, acc, 0, 0, 0);
        acc = __builtin_amdgcn_mfma_f32_16x16x32_f16(a1, b1, acc, 0, 0, 0);
        acc = __builtin_amdgcn_mfma_f32_16x16x32_f16(a2, b2, acc, 0, 0, 0);
        acc = __builtin_amdgcn_mfma_f32_16x16x32_f16(a3, b3, acc, 0, 0, 0);
#pragma unroll
        for (int j = 0; j < 4; ++j)
            s_out[orow + j][col] = acc[j];
    }
    __syncthreads();

    // ---- epilogue: 4 threads/node, 16 ch each: +bias +residual, LN, relu, pack ----
    int nb = t >> 2;                              // node-in-block 0..63
    int q  = t & 3;                               // channel quarter
    int node2 = blockIdx.x * 64 + nb;
    const float* srow = &s_out[nb][q * 16];
    const float* b2   = bias + q * 16;
    float v[16];
#pragma unroll
    for (int i = 0; i < 16; ++i) v[i] = srow[i] + b2[i];

    const uint4* xr = (const uint4*)(xh + (size_t)node2 * HF + q * 16);
    uint4 r0 = xr[0], r1 = xr[1];
    {
        float2 f;
        f = upk_f16(r0.x); v[0] += f.x;  v[1] += f.y;
        f = upk_f16(r0.y); v[2] += f.x;  v[3] += f.y;
        f = upk_f16(r0.z); v[4] += f.x;  v[5] += f.y;
        f = upk_f16(r0.w); v[6] += f.x;  v[7] += f.y;
        f = upk_f16(r1.x); v[8] += f.x;  v[9] += f.y;
        f = upk_f16(r1.y); v[10] += f.x; v[11] += f.y;
        f = upk_f16(r1.z); v[12] += f.x; v[13] += f.y;
        f = upk_f16(r1.w); v[14] += f.x; v[15] += f.y;
    }
    float ps = 0.f, pq = 0.f;
#pragma unroll
    for (int i = 0; i < 16; ++i) { ps += v[i]; pq += v[i] * v[i]; }
    ps += __shfl_xor(ps, 1, 64); ps += __shfl_xor(ps, 2, 64);
    pq += __shfl_xor(pq, 1, 64); pq += __shfl_xor(pq, 2, 64);
    float mu  = ps * (1.f / HF);
    float var = pq * (1.f / HF) - mu * mu;
    float rs  = rsqrtf(var + LN_EPS);

    const float* g2  = g    + q * 16;
    const float* be2 = beta + q * 16;
    float y[16];
#pragma unroll
    for (int i = 0; i < 16; ++i)
        y[i] = fmaxf((v[i] - mu) * rs * g2[i] + be2[i], 0.f);

    uint4* hdst = (uint4*)(xh + (size_t)node2 * HF + q * 16);
    uint4 o0, o1;
    o0.x = pk_f16(y[0],  y[1]);  o0.y = pk_f16(y[2],  y[3]);
    o0.z = pk_f16(y[4],  y[5]);  o0.w = pk_f16(y[6],  y[7]);
    o1.x = pk_f16(y[8],  y[9]);  o1.y = pk_f16(y[10], y[11]);
    o1.z = pk_f16(y[12], y[13]); o1.w = pk_f16(y[14], y[15]);
    hdst[0] = o0; hdst[1] = o1;
}

// ---------------- output head: out = xh@out_w + out_b (2 threads/node, fp32 out) ----------------
__global__ __launch_bounds__(256) void out_kernel(const __half* __restrict__ xh,
                                                  const float* __restrict__ W,
                                                  const float* __restrict__ bias,
                                                  float* __restrict__ out)
{
    int lane = threadIdx.x & 63;
    int waveid = threadIdx.x >> 6;
    int half = __builtin_amdgcn_readfirstlane(waveid & 1);   // pin uniformity
    int nib = (waveid >> 1) * 64 + lane;
    int node = blockIdx.x * 128 + nib;
    const uint4* rp = (const uint4*)(xh + (size_t)node * HF);

    float o[16];
    const float* b2 = bias + half * 16;
#pragma unroll
    for (int j = 0; j < 16; ++j) o[j] = b2[j];

#pragma unroll 1
    for (int kc = 0; kc < HF; kc += 16) {
        uint4 u0 = rp[kc >> 3];
        uint4 u1 = rp[(kc >> 3) + 1];
        float av[16];
        float2 f;
        f = upk_f16(u0.x); av[0]=f.x;  av[1]=f.y;
        f = upk_f16(u0.y); av[2]=f.x;  av[3]=f.y;
        f = upk_f16(u0.z); av[4]=f.x;  av[5]=f.y;
        f = upk_f16(u0.w); av[6]=f.x;  av[7]=f.y;
        f = upk_f16(u1.x); av[8]=f.x;  av[9]=f.y;
        f = upk_f16(u1.y); av[10]=f.x; av[11]=f.y;
        f = upk_f16(u1.z); av[12]=f.x; av[13]=f.y;
        f = upk_f16(u1.w); av[14]=f.x; av[15]=f.y;
#pragma unroll
        for (int u = 0; u < 16; ++u) {
            const float* wr = W + (kc + u) * OUTF + half * 16;   // uniform -> s_load
#pragma unroll
            for (int j = 0; j < 16; ++j) o[j] = fmaf(av[u], wr[j], o[j]);
        }
    }

    float4* dst = (float4*)(out + (size_t)node * OUTF + half * 16);
#pragma unroll
    for (int q = 0; q < 4; ++q) {
        float4 v; v.x = o[4*q]; v.y = o[4*q+1]; v.z = o[4*q+2]; v.w = o[4*q+3];
        dst[q] = v;
    }
}

extern "C" void kernel_launch(void* const* d_in, const int* in_sizes, int n_in,
                              void* d_out, int out_size, void* d_ws, size_t ws_size,
                              hipStream_t stream)
{
    const float* nf     = (const float*)d_in[0];
    const int*   ei     = (const int*)  d_in[1];   // edge_indices (B,2,E)
    const float* enc_w1 = (const float*)d_in[3];
    const float* enc_b1 = (const float*)d_in[4];
    const float* enc_w2 = (const float*)d_in[5];
    const float* enc_b2 = (const float*)d_in[6];
    const float* conv_w = (const float*)d_in[7];   // (3,128,64)
    const float* conv_b = (const float*)d_in[8];   // (3,64)
    const float* ln_g   = (const float*)d_in[9];
    const float* ln_b   = (const float*)d_in[10];
    const float* out_w  = (const float*)d_in[11];  // (64,32)
    const float* out_b  = (const float*)d_in[12];

    // workspace (~53 MB); bkt aliases agh (bucket data dead once fill2 runs)
    char* w = (char*)d_ws;
    __half* xh   = (__half*)w;  w += (size_t)NODES * HF * 2;              // 20.5 MB
    __half* agh  = (__half*)w;  w += (size_t)NODES * HF * 2;              // 20.5 MB
    unsigned* bkt = (unsigned*)agh;   // 256 buckets * 16384 * 4B = 16.8 MB
    int* cnt     = (int*)w;     w += (size_t)NODES * sizeof(int);
    int* off     = (int*)w;     w += (size_t)NODES * sizeof(int);
    int* csr     = (int*)w;     w += (size_t)NB * NE * sizeof(int);       // 10.24 MB
    int* gcur    = (int*)w;                                               // 256 ints

    hipMemsetAsync(gcur, 0, 256 * sizeof(int), stream);

    enc_kernel<<<NODES / 128, 256, 0, stream>>>(nf, enc_w1, enc_b1, enc_w2, enc_b2, xh);
    bucket_kernel<<<NB * NCHUNK, 256, 0, stream>>>(ei, gcur, bkt);
    count2_kernel<<<NB * 16, 512, 0, stream>>>(bkt, gcur, cnt);
    scan_kernel<<<NB, 256, 0, stream>>>(cnt, off);
    fill2_kernel<<<NB * 16, 512, 0, stream>>>(bkt, gcur, off, csr);

    for (int l = 0; l < 3; ++l) {
        agg_kernel<<<NODES / 4, 256, 0, stream>>>(xh, cnt, off, csr, agh);
        conv_kernel<<<NODES / 64, 256, 0, stream>>>(xh, agh,
                                                    conv_w + (size_t)l * 2 * HF * HF,
                                                    conv_b + (size_t)l * HF,
                                                    ln_g + (size_t)l * HF,
                                                    ln_b + (size_t)l * HF);
    }
    out_kernel<<<NODES / 128, 256, 0, stream>>>(xh, out_w, out_b, (float*)d_out);
}

// Round 16
// 393.824 us; speedup vs baseline: 1.0137x; 1.0137x over previous
//
#include <hip/hip_runtime.h>
#include <hip/hip_fp16.h>

#define NB   16       // batches
#define NN   10000    // nodes per batch
#define NE   160000   // edges per batch
#define NODES (NB*NN) // 160000 total nodes
#define IN_F 19
#define HF   64
#define OUTF 32
#define LN_EPS 1e-5f
#define RANGE 625     // dst nodes per bucket (16 buckets/batch)
#define NCHUNK 32     // edge chunks per batch in bucket_kernel
#define CHSZ (NE/NCHUNK)   // 5000 edges per chunk
#define BCAP 16384    // bucket capacity (entries); mean 10000, sigma ~97

// R29 = R27 BYTE-IDENTICAL REVERT (pre-commit honored: R28 total 399.2 > 392).
// R28 post-mortem: 2thr/node enc fixed the spill (VGPR 56, WRITE 20MB clean)
// but launch_bounds(256,2) + s_load latency left occupancy at 2.3 waves/SIMD
// -> enc 52-57us, net -7us. enc variants explored (spill/occupancy/latency)
// all land 44-57us; further draws have negative EV at 40% fail-rate.
// R27 config: fused enc (1thr/node, k-unrolled), agg R21-form + XCD map,
// conv 1-tile MFMA (FROZEN), out 2thr/node VALU. 392.0us / absmax 0.015625.

__device__ inline unsigned pk_f16(float a, float b) {
    __half2 h = __float22half2_rn(float2{a, b});
    return *(unsigned*)&h;
}
__device__ inline float2 upk_f16(unsigned u) {
    __half2 h = *(__half2*)&u;
    return __half22float2(h);
}

typedef _Float16 f16x8 __attribute__((ext_vector_type(8)));
typedef float    f32x4 __attribute__((ext_vector_type(4)));

// ---------------- enc (fused, spill-free): xh = relu(nf@W1+b1)@W2 + b2 ----------------
__global__ __launch_bounds__(256) void enc_kernel(
    const float* __restrict__ nf,
    const float* __restrict__ w1, const float* __restrict__ b1,
    const float* __restrict__ w2, const float* __restrict__ b2,
    __half* __restrict__ xh)
{
    int node = blockIdx.x * 256 + threadIdx.x;   // 625*256 = 160000 exactly
    const float* p = nf + (size_t)node * IN_F;
    float a[IN_F];
#pragma unroll
    for (int k = 0; k < IN_F; ++k) a[k] = p[k];

    float h[HF];
#pragma unroll
    for (int j = 0; j < HF; ++j) h[j] = b1[j];
#pragma unroll
    for (int k = 0; k < IN_F; ++k) {
        float ak = a[k];
        const float* wr = w1 + k * HF;           // wave-uniform -> s_load
#pragma unroll
        for (int j = 0; j < HF; ++j) h[j] = fmaf(ak, wr[j], h[j]);
    }
#pragma unroll
    for (int j = 0; j < HF; ++j) h[j] = fmaxf(h[j], 0.f);

    // second GEMM straight from registers; k fully unrolled so h[k] is
    // compile-time indexed (NO scratch); two 32-col halves cap acc VGPRs
    uint4* dst = (uint4*)(xh + (size_t)node * HF);
#pragma unroll 1
    for (int hb = 0; hb < 2; ++hb) {
        float acc[32];
        const float* b2h = b2 + hb * 32;
#pragma unroll
        for (int j = 0; j < 32; ++j) acc[j] = b2h[j];
        const float* wbase = w2 + hb * 32;       // uniform offset
#pragma unroll
        for (int k = 0; k < HF; ++k) {
            const float* wr = wbase + k * HF;    // uniform -> s_load
            float ak = h[k];
#pragma unroll
            for (int j = 0; j < 32; ++j) acc[j] = fmaf(ak, wr[j], acc[j]);
        }
#pragma unroll
        for (int q = 0; q < 4; ++q) {
            uint4 u;
            u.x = pk_f16(acc[8*q+0], acc[8*q+1]);
            u.y = pk_f16(acc[8*q+2], acc[8*q+3]);
            u.z = pk_f16(acc[8*q+4], acc[8*q+5]);
            u.w = pk_f16(acc[8*q+6], acc[8*q+7]);
            dst[hb * 4 + q] = u;
        }
    }
}

// ---------------- bucket: bin edge chunks into per-(batch,range) buckets ----------------
__global__ __launch_bounds__(256) void bucket_kernel(const int* __restrict__ ei,
                                                     int* __restrict__ gcur,
                                                     unsigned* __restrict__ bkt)
{
    __shared__ int lcnt[16];
    __shared__ int lcur[16];
    __shared__ int gbase[16];
    int b = blockIdx.x >> 5;                     // NCHUNK=32 chunks per batch
    int chunk = blockIdx.x & 31;
    int t = threadIdx.x;
    if (t < 16) { lcnt[t] = 0; lcur[t] = 0; }
    __syncthreads();

    const int* srcp = ei + (size_t)b * 2 * NE + chunk * CHSZ;
    const int* dstp = srcp + NE;

    for (int e = t; e < CHSZ; e += 256)
        atomicAdd(&lcnt[(unsigned)dstp[e] / RANGE], 1);
    __syncthreads();
    if (t < 16) gbase[t] = atomicAdd(&gcur[b * 16 + t], lcnt[t]);
    __syncthreads();

    for (int e = t; e < CHSZ; e += 256) {
        int d = dstp[e];                          // L1-hot (2nd pass)
        int s = srcp[e];
        int j = (unsigned)d / RANGE;
        int ld = d - j * RANGE;
        int pos = gbase[j] + atomicAdd(&lcur[j], 1);
        if (pos < BCAP)
            bkt[(size_t)(b * 16 + j) * BCAP + pos] = (unsigned)s | ((unsigned)ld << 16);
    }
}

// ---------------- count2: per-bucket histogram -> cnt ----------------
__global__ __launch_bounds__(512) void count2_kernel(const unsigned* __restrict__ bkt,
                                                     const int* __restrict__ gcur,
                                                     int* __restrict__ cnt)
{
    __shared__ int lcnt[RANGE];
    int bid = blockIdx.x;                        // b*16 + j
    int b = bid >> 4, j = bid & 15;
    int t = threadIdx.x;
    for (int i = t; i < RANGE; i += 512) lcnt[i] = 0;
    __syncthreads();
    int n = min(gcur[bid], BCAP);
    const unsigned* bp = bkt + (size_t)bid * BCAP;
    for (int e = t; e < n; e += 512) atomicAdd(&lcnt[bp[e] >> 16], 1);
    __syncthreads();
    int base = b * NN + j * RANGE;
    for (int i = t; i < RANGE; i += 512) cnt[base + i] = lcnt[i];
}

// ---------------- scan: per-batch exclusive prefix over cnt ----------------
__global__ __launch_bounds__(256) void scan_kernel(const int* __restrict__ cnt, int* __restrict__ off)
{
    __shared__ int sdata[256];
    int b = blockIdx.x, t = threadIdx.x;
    const int CH = 40;                          // 256*40 = 10240 >= NN
    int lo = t * CH, hi = min(lo + CH, NN);
    int s = 0;
    for (int i = lo; i < hi; ++i) s += cnt[b * NN + i];
    sdata[t] = s;
    __syncthreads();
    for (int ofs = 1; ofs < 256; ofs <<= 1) {
        int v = (t >= ofs) ? sdata[t - ofs] : 0;
        __syncthreads();
        sdata[t] += v;
        __syncthreads();
    }
    int run = (t > 0) ? sdata[t - 1] : 0;       // exclusive prefix
    for (int i = lo; i < hi; ++i) { off[b * NN + i] = run; run += cnt[b * NN + i]; }
}

// ---------------- fill2: per-bucket fill of the block-owned CSR segment ----------------
__global__ __launch_bounds__(512) void fill2_kernel(const unsigned* __restrict__ bkt,
                                                    const int* __restrict__ gcur,
                                                    const int* __restrict__ off,
                                                    int* __restrict__ csr)
{
    __shared__ int lcur[RANGE];
    int bid = blockIdx.x;                        // b*16 + j
    int b = bid >> 4, j = bid & 15;
    int t = threadIdx.x;
    for (int i = t; i < RANGE; i += 512) lcur[i] = 0;
    __syncthreads();
    int n = min(gcur[bid], BCAP);
    const unsigned* bp = bkt + (size_t)bid * BCAP;
    const int* offb = off + b * NN + j * RANGE;
    int* csrb = csr + (size_t)b * NE;
    for (int e = t; e < n; e += 512) {
        unsigned u = bp[e];
        int ld = u >> 16;
        int pos = offb[ld] + atomicAdd(&lcur[ld], 1);
        csrb[pos] = (int)(u & 0xffffu);          // block-exclusive ~40KB segment
    }
}

// ---------------- mean aggregation (R25 verbatim): R21 FP code, XCD-pinned map ----
__global__ __launch_bounds__(256) void agg_kernel(const __half* __restrict__ xh,
                                                  const int* __restrict__ cnt,
                                                  const int* __restrict__ off,
                                                  const int* __restrict__ csr,
                                                  __half* __restrict__ aggh)
{
    int bid = blockIdx.x;
    int x = bid & 7;                                // presumed XCD slot
    int r = bid >> 3;                               // 0..4999
    int b = x + ((r & 1) << 3);                     // batch: XCD x -> {x, x+8}
    int chunk = r >> 1;                             // 0..2499  (bijective map)
    int wid = threadIdx.x >> 6;                     // 4 waves = 4 nodes per block
    int n = chunk * 4 + wid;                        // 0..9999
    int w = b * NN + n;
    w = __builtin_amdgcn_readfirstlane(w);          // wave-uniform -> scalar loads
    int lane = threadIdx.x & 63;
    unsigned g  = (unsigned)(lane >> 5);            // edge group 0/1
    unsigned cl = (unsigned)(lane & 31);            // uint index = 2 channels
    int c = cnt[w];
    int o = off[w];
    const int* row = csr + (size_t)b * NE + o;      // uniform -> s_load
    const unsigned* xbu = (const unsigned*)(xh + (size_t)b * NN * HF);
    float a0 = 0.f, a1 = 0.f;
    int t = 0;
    for (; t + 16 <= c; t += 16) {                  // 16 edges/iter, 8 gathers in flight
        int i0 = row[t],    i1 = row[t+1],  i2 = row[t+2],  i3 = row[t+3];
        int i4 = row[t+4],  i5 = row[t+5],  i6 = row[t+6],  i7 = row[t+7];
        int i8 = row[t+8],  i9 = row[t+9],  iA = row[t+10], iB = row[t+11];
        int iC = row[t+12], iD = row[t+13], iE = row[t+14], iF = row[t+15];
        unsigned j0 = (unsigned)(g ? i1 : i0);
        unsigned j1 = (unsigned)(g ? i3 : i2);
        unsigned j2 = (unsigned)(g ? i5 : i4);
        unsigned j3 = (unsigned)(g ? i7 : i6);
        unsigned j4 = (unsigned)(g ? i9 : i8);
        unsigned j5 = (unsigned)(g ? iB : iA);
        unsigned j6 = (unsigned)(g ? iD : iC);
        unsigned j7 = (unsigned)(g ? iF : iE);
        unsigned u0 = xbu[j0 * 32u + cl];
        unsigned u1 = xbu[j1 * 32u + cl];
        unsigned u2 = xbu[j2 * 32u + cl];
        unsigned u3 = xbu[j3 * 32u + cl];
        unsigned u4 = xbu[j4 * 32u + cl];
        unsigned u5 = xbu[j5 * 32u + cl];
        unsigned u6 = xbu[j6 * 32u + cl];
        unsigned u7 = xbu[j7 * 32u + cl];
        float2 f0 = upk_f16(u0), f1 = upk_f16(u1), f2 = upk_f16(u2), f3 = upk_f16(u3);
        float2 f4 = upk_f16(u4), f5 = upk_f16(u5), f6 = upk_f16(u6), f7 = upk_f16(u7);
        a0 += f0.x; a1 += f0.y;
        a0 += f1.x; a1 += f1.y;
        a0 += f2.x; a1 += f2.y;
        a0 += f3.x; a1 += f3.y;
        a0 += f4.x; a1 += f4.y;
        a0 += f5.x; a1 += f5.y;
        a0 += f6.x; a1 += f6.y;
        a0 += f7.x; a1 += f7.y;
    }
    if (t + 8 <= c) {                               // one R14 8-edge body
        int i0 = row[t],   i1 = row[t+1], i2 = row[t+2], i3 = row[t+3];
        int i4 = row[t+4], i5 = row[t+5], i6 = row[t+6], i7 = row[t+7];
        unsigned j0 = (unsigned)(g ? i1 : i0);
        unsigned j1 = (unsigned)(g ? i3 : i2);
        unsigned j2 = (unsigned)(g ? i5 : i4);
        unsigned j3 = (unsigned)(g ? i7 : i6);
        unsigned u0 = xbu[j0 * 32u + cl];
        unsigned u1 = xbu[j1 * 32u + cl];
        unsigned u2 = xbu[j2 * 32u + cl];
        unsigned u3 = xbu[j3 * 32u + cl];
        float2 f0 = upk_f16(u0), f1 = upk_f16(u1), f2 = upk_f16(u2), f3 = upk_f16(u3);
        a0 += f0.x; a1 += f0.y;
        a0 += f1.x; a1 += f1.y;
        a0 += f2.x; a1 += f2.y;
        a0 += f3.x; a1 += f3.y;
        t += 8;
    }
    for (; t + 2 <= c; t += 2) {
        int i0 = row[t], i1 = row[t+1];
        unsigned j = (unsigned)(g ? i1 : i0);
        float2 f = upk_f16(xbu[j * 32u + cl]);
        a0 += f.x; a1 += f.y;
    }
    if (t < c && g == 0) {                          // odd leftover: group 0 only
        float2 f = upk_f16(xbu[(unsigned)row[t] * 32u + cl]);
        a0 += f.x; a1 += f.y;
    }
    a0 += __shfl_xor(a0, 32, 64);                   // cross-group reduce
    a1 += __shfl_xor(a1, 32, 64);
    float inv = (c > 0) ? 1.f / (float)c : 0.f;
    unsigned pk = pk_f16(a0 * inv, a1 * inv);
    if (g == 0) ((unsigned*)aggh)[(size_t)w * 32 + cl] = pk;
}

// ---------------- conv (MFMA, R21/R14 form, FROZEN): 64 nodes/block ----------------
__global__ __launch_bounds__(256) void conv_kernel(
    __half* __restrict__ xh, const __half* __restrict__ aggh,
    const float* __restrict__ W, const float* __restrict__ bias,
    const float* __restrict__ g, const float* __restrict__ beta)
{
    __shared__ __half Wt[64][136];    // Wt[col][k] = f16(W[k][col]); stride 136: 16B-aligned
    __shared__ float s_out[64][68];   // fp32 matmul result; stride 68: 16B-aligned

    int t = threadIdx.x;

    // ---- stage W^T as f16 into LDS (coalesced global reads) ----
    {
        int c  = t & 63;
        int kb = (t >> 6) * 32;                   // wave w covers k rows kb..kb+31
#pragma unroll
        for (int k = 0; k < 32; k += 2) {
            float w0 = W[(size_t)(kb + k)     * HF + c];
            float w1 = W[(size_t)(kb + k + 1) * HF + c];
            *(__half2*)&Wt[c][kb + k] = __float22half2_rn(float2{w0, w1});
        }
    }
    __syncthreads();

    // ---- per-wave 16x64 output tile via 16 MFMAs ----
    int l     = t & 63;
    int wv    = t >> 6;                           // wave 0..3 -> node rows wv*16..wv*16+15
    int arow16 = l & 15;                          // A-frag row within tile
    int ks    = (l >> 4) * 8;                     // A/B-frag k-slot base: 0,8,16,24
    int node  = blockIdx.x * 64 + wv * 16 + arow16;

    const __half* xrow = xh   + (size_t)node * HF;
    const __half* grow = aggh + (size_t)node * HF;
    f16x8 a0 = *(const f16x8*)(xrow + ks);        // k =   0+ks..   (x half, W rows 0..63)
    f16x8 a1 = *(const f16x8*)(xrow + 32 + ks);   // k =  32+ks..
    f16x8 a2 = *(const f16x8*)(grow + ks);        // k =  64+ks..   (agg half, W rows 64..127)
    f16x8 a3 = *(const f16x8*)(grow + 32 + ks);   // k =  96+ks..

    int orow = wv * 16 + (l >> 4) * 4;            // D rows this lane holds (reg j -> orow+j)
#pragma unroll
    for (int ct = 0; ct < 4; ++ct) {              // 4 column tiles of 16
        int col = (l & 15) + ct * 16;
        f16x8 b0 = *(const f16x8*)&Wt[col][ks];
        f16x8 b1 = *(const f16x8*)&Wt[col][32 + ks];
        f16x8 b2 = *(const f16x8*)&Wt[col][64 + ks];
        f16x8 b3 = *(const f16x8*)&Wt[col][96 + ks];
        f32x4 acc = {0.f, 0.f, 0.f, 0.f};
        acc = __builtin_amdgcn_mfma_f32_16x16x32_f16(a0, b0, acc, 0, 0, 0);
        acc = __builtin_amdgcn_mfma_f32_16x16x32_f16(a1, b1, acc, 0, 0, 0);
        acc = __builtin_amdgcn_mfma_f32_16x16x32_f16(a2, b2, acc, 0, 0, 0);
        acc = __builtin_amdgcn_mfma_f32_16x16x32_f16(a3, b3, acc, 0, 0, 0);
#pragma unroll
        for (int j = 0; j < 4; ++j)
            s_out[orow + j][col] = acc[j];
    }
    __syncthreads();

    // ---- epilogue: 4 threads/node, 16 ch each: +bias +residual, LN, relu, pack ----
    int nb = t >> 2;                              // node-in-block 0..63
    int q  = t & 3;                               // channel quarter
    int node2 = blockIdx.x * 64 + nb;
    const float* srow = &s_out[nb][q * 16];
    const float* b2   = bias + q * 16;
    float v[16];
#pragma unroll
    for (int i = 0; i < 16; ++i) v[i] = srow[i] + b2[i];

    const uint4* xr = (const uint4*)(xh + (size_t)node2 * HF + q * 16);
    uint4 r0 = xr[0], r1 = xr[1];
    {
        float2 f;
        f = upk_f16(r0.x); v[0] += f.x;  v[1] += f.y;
        f = upk_f16(r0.y); v[2] += f.x;  v[3] += f.y;
        f = upk_f16(r0.z); v[4] += f.x;  v[5] += f.y;
        f = upk_f16(r0.w); v[6] += f.x;  v[7] += f.y;
        f = upk_f16(r1.x); v[8] += f.x;  v[9] += f.y;
        f = upk_f16(r1.y); v[10] += f.x; v[11] += f.y;
        f = upk_f16(r1.z); v[12] += f.x; v[13] += f.y;
        f = upk_f16(r1.w); v[14] += f.x; v[15] += f.y;
    }
    float ps = 0.f, pq = 0.f;
#pragma unroll
    for (int i = 0; i < 16; ++i) { ps += v[i]; pq += v[i] * v[i]; }
    ps += __shfl_xor(ps, 1, 64); ps += __shfl_xor(ps, 2, 64);
    pq += __shfl_xor(pq, 1, 64); pq += __shfl_xor(pq, 2, 64);
    float mu  = ps * (1.f / HF);
    float var = pq * (1.f / HF) - mu * mu;
    float rs  = rsqrtf(var + LN_EPS);

    const float* g2  = g    + q * 16;
    const float* be2 = beta + q * 16;
    float y[16];
#pragma unroll
    for (int i = 0; i < 16; ++i)
        y[i] = fmaxf((v[i] - mu) * rs * g2[i] + be2[i], 0.f);

    uint4* hdst = (uint4*)(xh + (size_t)node2 * HF + q * 16);
    uint4 o0, o1;
    o0.x = pk_f16(y[0],  y[1]);  o0.y = pk_f16(y[2],  y[3]);
    o0.z = pk_f16(y[4],  y[5]);  o0.w = pk_f16(y[6],  y[7]);
    o1.x = pk_f16(y[8],  y[9]);  o1.y = pk_f16(y[10], y[11]);
    o1.z = pk_f16(y[12], y[13]); o1.w = pk_f16(y[14], y[15]);
    hdst[0] = o0; hdst[1] = o1;
}

// ---------------- output head: out = xh@out_w + out_b (2 threads/node, fp32 out) ----------------
__global__ __launch_bounds__(256) void out_kernel(const __half* __restrict__ xh,
                                                  const float* __restrict__ W,
                                                  const float* __restrict__ bias,
                                                  float* __restrict__ out)
{
    int lane = threadIdx.x & 63;
    int waveid = threadIdx.x >> 6;
    int half = __builtin_amdgcn_readfirstlane(waveid & 1);   // pin uniformity
    int nib = (waveid >> 1) * 64 + lane;
    int node = blockIdx.x * 128 + nib;
    const uint4* rp = (const uint4*)(xh + (size_t)node * HF);

    float o[16];
    const float* b2 = bias + half * 16;
#pragma unroll
    for (int j = 0; j < 16; ++j) o[j] = b2[j];

#pragma unroll 1
    for (int kc = 0; kc < HF; kc += 16) {
        uint4 u0 = rp[kc >> 3];
        uint4 u1 = rp[(kc >> 3) + 1];
        float av[16];
        float2 f;
        f = upk_f16(u0.x); av[0]=f.x;  av[1]=f.y;
        f = upk_f16(u0.y); av[2]=f.x;  av[3]=f.y;
        f = upk_f16(u0.z); av[4]=f.x;  av[5]=f.y;
        f = upk_f16(u0.w); av[6]=f.x;  av[7]=f.y;
        f = upk_f16(u1.x); av[8]=f.x;  av[9]=f.y;
        f = upk_f16(u1.y); av[10]=f.x; av[11]=f.y;
        f = upk_f16(u1.z); av[12]=f.x; av[13]=f.y;
        f = upk_f16(u1.w); av[14]=f.x; av[15]=f.y;
#pragma unroll
        for (int u = 0; u < 16; ++u) {
            const float* wr = W + (kc + u) * OUTF + half * 16;   // uniform -> s_load
#pragma unroll
            for (int j = 0; j < 16; ++j) o[j] = fmaf(av[u], wr[j], o[j]);
        }
    }

    float4* dst = (float4*)(out + (size_t)node * OUTF + half * 16);
#pragma unroll
    for (int q = 0; q < 4; ++q) {
        float4 v; v.x = o[4*q]; v.y = o[4*q+1]; v.z = o[4*q+2]; v.w = o[4*q+3];
        dst[q] = v;
    }
}

extern "C" void kernel_launch(void* const* d_in, const int* in_sizes, int n_in,
                              void* d_out, int out_size, void* d_ws, size_t ws_size,
                              hipStream_t stream)
{
    const float* nf     = (const float*)d_in[0];
    const int*   ei     = (const int*)  d_in[1];   // edge_indices (B,2,E)
    const float* enc_w1 = (const float*)d_in[3];
    const float* enc_b1 = (const float*)d_in[4];
    const float* enc_w2 = (const float*)d_in[5];
    const float* enc_b2 = (const float*)d_in[6];
    const float* conv_w = (const float*)d_in[7];   // (3,128,64)
    const float* conv_b = (const float*)d_in[8];   // (3,64)
    const float* ln_g   = (const float*)d_in[9];
    const float* ln_b   = (const float*)d_in[10];
    const float* out_w  = (const float*)d_in[11];  // (64,32)
    const float* out_b  = (const float*)d_in[12];

    // workspace (~53 MB); bkt aliases agh (bucket data dead once fill2 runs)
    char* w = (char*)d_ws;
    __half* xh   = (__half*)w;  w += (size_t)NODES * HF * 2;              // 20.5 MB
    __half* agh  = (__half*)w;  w += (size_t)NODES * HF * 2;              // 20.5 MB
    unsigned* bkt = (unsigned*)agh;   // 256 buckets * 16384 * 4B = 16.8 MB
    int* cnt     = (int*)w;     w += (size_t)NODES * sizeof(int);
    int* off     = (int*)w;     w += (size_t)NODES * sizeof(int);
    int* csr     = (int*)w;     w += (size_t)NB * NE * sizeof(int);       // 10.24 MB
    int* gcur    = (int*)w;                                               // 256 ints

    hipMemsetAsync(gcur, 0, 256 * sizeof(int), stream);

    enc_kernel<<<NODES / 256, 256, 0, stream>>>(nf, enc_w1, enc_b1, enc_w2, enc_b2, xh);
    bucket_kernel<<<NB * NCHUNK, 256, 0, stream>>>(ei, gcur, bkt);
    count2_kernel<<<NB * 16, 512, 0, stream>>>(bkt, gcur, cnt);
    scan_kernel<<<NB, 256, 0, stream>>>(cnt, off);
    fill2_kernel<<<NB * 16, 512, 0, stream>>>(bkt, gcur, off, csr);

    for (int l = 0; l < 3; ++l) {
        agg_kernel<<<NODES / 4, 256, 0, stream>>>(xh, cnt, off, csr, agh);
        conv_kernel<<<NODES / 64, 256, 0, stream>>>(xh, agh,
                                                    conv_w + (size_t)l * 2 * HF * HF,
                                                    conv_b + (size_t)l * HF,
                                                    ln_g + (size_t)l * HF,
                                                    ln_b + (size_t)l * HF);
    }
    out_kernel<<<NODES / 128, 256, 0, stream>>>(xh, out_w, out_b, (float*)d_out);
}

// Round 17
// 391.715 us; speedup vs baseline: 1.0191x; 1.0054x over previous
//
#include <hip/hip_runtime.h>
#include <hip/hip_fp16.h>

#define NB   16       // batches
#define NN   10000    // nodes per batch
#define NE   160000   // edges per batch
#define NODES (NB*NN) // 160000 total nodes
#define IN_F 19
#define HF   64
#define OUTF 32
#define LN_EPS 1e-5f
#define RANGE 625     // dst nodes per bucket (16 buckets/batch)
#define NCHUNK 32     // edge chunks per batch in bucket_kernel
#define CHSZ (NE/NCHUNK)   // 5000 edges per chunk
#define BCAP 16384    // bucket capacity (entries); mean 10000, sigma ~97

// R30 = R29 + ONE TOKEN: enc __launch_bounds__(256) -> (256, 1).
// R29 counters: enc VGPR capped at 84 -> residual spill (WRITE 27.4MB vs
// 20.5 ideal). min-waves=1 lifts the VGPR cap; grid (625 blocks = 2.4
// waves/SIMD) can't use high occupancy anyway, so nothing lost.
// Risk re-rated from full ledger: ALL 5 fails contained conv-2-tile; ALL 10
// non-conv-touching rounds passed (absmax 0.0156-0.039). conv/agg/out/CSR
// byte-identical to R29 (392-394us, absmax 0.015625).
// Pre-commit: total > 394 or absmax >= 0.065 -> final answer is R29 verbatim.

__device__ inline unsigned pk_f16(float a, float b) {
    __half2 h = __float22half2_rn(float2{a, b});
    return *(unsigned*)&h;
}
__device__ inline float2 upk_f16(unsigned u) {
    __half2 h = *(__half2*)&u;
    return __half22float2(h);
}

typedef _Float16 f16x8 __attribute__((ext_vector_type(8)));
typedef float    f32x4 __attribute__((ext_vector_type(4)));

// ---------------- enc (fused, spill-free): xh = relu(nf@W1+b1)@W2 + b2 ----------------
__global__ __launch_bounds__(256, 1) void enc_kernel(
    const float* __restrict__ nf,
    const float* __restrict__ w1, const float* __restrict__ b1,
    const float* __restrict__ w2, const float* __restrict__ b2,
    __half* __restrict__ xh)
{
    int node = blockIdx.x * 256 + threadIdx.x;   // 625*256 = 160000 exactly
    const float* p = nf + (size_t)node * IN_F;
    float a[IN_F];
#pragma unroll
    for (int k = 0; k < IN_F; ++k) a[k] = p[k];

    float h[HF];
#pragma unroll
    for (int j = 0; j < HF; ++j) h[j] = b1[j];
#pragma unroll
    for (int k = 0; k < IN_F; ++k) {
        float ak = a[k];
        const float* wr = w1 + k * HF;           // wave-uniform -> s_load
#pragma unroll
        for (int j = 0; j < HF; ++j) h[j] = fmaf(ak, wr[j], h[j]);
    }
#pragma unroll
    for (int j = 0; j < HF; ++j) h[j] = fmaxf(h[j], 0.f);

    // second GEMM straight from registers; k fully unrolled so h[k] is
    // compile-time indexed (NO scratch); two 32-col halves cap acc VGPRs
    uint4* dst = (uint4*)(xh + (size_t)node * HF);
#pragma unroll 1
    for (int hb = 0; hb < 2; ++hb) {
        float acc[32];
        const float* b2h = b2 + hb * 32;
#pragma unroll
        for (int j = 0; j < 32; ++j) acc[j] = b2h[j];
        const float* wbase = w2 + hb * 32;       // uniform offset
#pragma unroll
        for (int k = 0; k < HF; ++k) {
            const float* wr = wbase + k * HF;    // uniform -> s_load
            float ak = h[k];
#pragma unroll
            for (int j = 0; j < 32; ++j) acc[j] = fmaf(ak, wr[j], acc[j]);
        }
#pragma unroll
        for (int q = 0; q < 4; ++q) {
            uint4 u;
            u.x = pk_f16(acc[8*q+0], acc[8*q+1]);
            u.y = pk_f16(acc[8*q+2], acc[8*q+3]);
            u.z = pk_f16(acc[8*q+4], acc[8*q+5]);
            u.w = pk_f16(acc[8*q+6], acc[8*q+7]);
            dst[hb * 4 + q] = u;
        }
    }
}

// ---------------- bucket: bin edge chunks into per-(batch,range) buckets ----------------
__global__ __launch_bounds__(256) void bucket_kernel(const int* __restrict__ ei,
                                                     int* __restrict__ gcur,
                                                     unsigned* __restrict__ bkt)
{
    __shared__ int lcnt[16];
    __shared__ int lcur[16];
    __shared__ int gbase[16];
    int b = blockIdx.x >> 5;                     // NCHUNK=32 chunks per batch
    int chunk = blockIdx.x & 31;
    int t = threadIdx.x;
    if (t < 16) { lcnt[t] = 0; lcur[t] = 0; }
    __syncthreads();

    const int* srcp = ei + (size_t)b * 2 * NE + chunk * CHSZ;
    const int* dstp = srcp + NE;

    for (int e = t; e < CHSZ; e += 256)
        atomicAdd(&lcnt[(unsigned)dstp[e] / RANGE], 1);
    __syncthreads();
    if (t < 16) gbase[t] = atomicAdd(&gcur[b * 16 + t], lcnt[t]);
    __syncthreads();

    for (int e = t; e < CHSZ; e += 256) {
        int d = dstp[e];                          // L1-hot (2nd pass)
        int s = srcp[e];
        int j = (unsigned)d / RANGE;
        int ld = d - j * RANGE;
        int pos = gbase[j] + atomicAdd(&lcur[j], 1);
        if (pos < BCAP)
            bkt[(size_t)(b * 16 + j) * BCAP + pos] = (unsigned)s | ((unsigned)ld << 16);
    }
}

// ---------------- count2: per-bucket histogram -> cnt ----------------
__global__ __launch_bounds__(512) void count2_kernel(const unsigned* __restrict__ bkt,
                                                     const int* __restrict__ gcur,
                                                     int* __restrict__ cnt)
{
    __shared__ int lcnt[RANGE];
    int bid = blockIdx.x;                        // b*16 + j
    int b = bid >> 4, j = bid & 15;
    int t = threadIdx.x;
    for (int i = t; i < RANGE; i += 512) lcnt[i] = 0;
    __syncthreads();
    int n = min(gcur[bid], BCAP);
    const unsigned* bp = bkt + (size_t)bid * BCAP;
    for (int e = t; e < n; e += 512) atomicAdd(&lcnt[bp[e] >> 16], 1);
    __syncthreads();
    int base = b * NN + j * RANGE;
    for (int i = t; i < RANGE; i += 512) cnt[base + i] = lcnt[i];
}

// ---------------- scan: per-batch exclusive prefix over cnt ----------------
__global__ __launch_bounds__(256) void scan_kernel(const int* __restrict__ cnt, int* __restrict__ off)
{
    __shared__ int sdata[256];
    int b = blockIdx.x, t = threadIdx.x;
    const int CH = 40;                          // 256*40 = 10240 >= NN
    int lo = t * CH, hi = min(lo + CH, NN);
    int s = 0;
    for (int i = lo; i < hi; ++i) s += cnt[b * NN + i];
    sdata[t] = s;
    __syncthreads();
    for (int ofs = 1; ofs < 256; ofs <<= 1) {
        int v = (t >= ofs) ? sdata[t - ofs] : 0;
        __syncthreads();
        sdata[t] += v;
        __syncthreads();
    }
    int run = (t > 0) ? sdata[t - 1] : 0;       // exclusive prefix
    for (int i = lo; i < hi; ++i) { off[b * NN + i] = run; run += cnt[b * NN + i]; }
}

// ---------------- fill2: per-bucket fill of the block-owned CSR segment ----------------
__global__ __launch_bounds__(512) void fill2_kernel(const unsigned* __restrict__ bkt,
                                                    const int* __restrict__ gcur,
                                                    const int* __restrict__ off,
                                                    int* __restrict__ csr)
{
    __shared__ int lcur[RANGE];
    int bid = blockIdx.x;                        // b*16 + j
    int b = bid >> 4, j = bid & 15;
    int t = threadIdx.x;
    for (int i = t; i < RANGE; i += 512) lcur[i] = 0;
    __syncthreads();
    int n = min(gcur[bid], BCAP);
    const unsigned* bp = bkt + (size_t)bid * BCAP;
    const int* offb = off + b * NN + j * RANGE;
    int* csrb = csr + (size_t)b * NE;
    for (int e = t; e < n; e += 512) {
        unsigned u = bp[e];
        int ld = u >> 16;
        int pos = offb[ld] + atomicAdd(&lcur[ld], 1);
        csrb[pos] = (int)(u & 0xffffu);          // block-exclusive ~40KB segment
    }
}

// ---------------- mean aggregation (R25 verbatim): R21 FP code, XCD-pinned map ----
__global__ __launch_bounds__(256) void agg_kernel(const __half* __restrict__ xh,
                                                  const int* __restrict__ cnt,
                                                  const int* __restrict__ off,
                                                  const int* __restrict__ csr,
                                                  __half* __restrict__ aggh)
{
    int bid = blockIdx.x;
    int x = bid & 7;                                // presumed XCD slot
    int r = bid >> 3;                               // 0..4999
    int b = x + ((r & 1) << 3);                     // batch: XCD x -> {x, x+8}
    int chunk = r >> 1;                             // 0..2499  (bijective map)
    int wid = threadIdx.x >> 6;                     // 4 waves = 4 nodes per block
    int n = chunk * 4 + wid;                        // 0..9999
    int w = b * NN + n;
    w = __builtin_amdgcn_readfirstlane(w);          // wave-uniform -> scalar loads
    int lane = threadIdx.x & 63;
    unsigned g  = (unsigned)(lane >> 5);            // edge group 0/1
    unsigned cl = (unsigned)(lane & 31);            // uint index = 2 channels
    int c = cnt[w];
    int o = off[w];
    const int* row = csr + (size_t)b * NE + o;      // uniform -> s_load
    const unsigned* xbu = (const unsigned*)(xh + (size_t)b * NN * HF);
    float a0 = 0.f, a1 = 0.f;
    int t = 0;
    for (; t + 16 <= c; t += 16) {                  // 16 edges/iter, 8 gathers in flight
        int i0 = row[t],    i1 = row[t+1],  i2 = row[t+2],  i3 = row[t+3];
        int i4 = row[t+4],  i5 = row[t+5],  i6 = row[t+6],  i7 = row[t+7];
        int i8 = row[t+8],  i9 = row[t+9],  iA = row[t+10], iB = row[t+11];
        int iC = row[t+12], iD = row[t+13], iE = row[t+14], iF = row[t+15];
        unsigned j0 = (unsigned)(g ? i1 : i0);
        unsigned j1 = (unsigned)(g ? i3 : i2);
        unsigned j2 = (unsigned)(g ? i5 : i4);
        unsigned j3 = (unsigned)(g ? i7 : i6);
        unsigned j4 = (unsigned)(g ? i9 : i8);
        unsigned j5 = (unsigned)(g ? iB : iA);
        unsigned j6 = (unsigned)(g ? iD : iC);
        unsigned j7 = (unsigned)(g ? iF : iE);
        unsigned u0 = xbu[j0 * 32u + cl];
        unsigned u1 = xbu[j1 * 32u + cl];
        unsigned u2 = xbu[j2 * 32u + cl];
        unsigned u3 = xbu[j3 * 32u + cl];
        unsigned u4 = xbu[j4 * 32u + cl];
        unsigned u5 = xbu[j5 * 32u + cl];
        unsigned u6 = xbu[j6 * 32u + cl];
        unsigned u7 = xbu[j7 * 32u + cl];
        float2 f0 = upk_f16(u0), f1 = upk_f16(u1), f2 = upk_f16(u2), f3 = upk_f16(u3);
        float2 f4 = upk_f16(u4), f5 = upk_f16(u5), f6 = upk_f16(u6), f7 = upk_f16(u7);
        a0 += f0.x; a1 += f0.y;
        a0 += f1.x; a1 += f1.y;
        a0 += f2.x; a1 += f2.y;
        a0 += f3.x; a1 += f3.y;
        a0 += f4.x; a1 += f4.y;
        a0 += f5.x; a1 += f5.y;
        a0 += f6.x; a1 += f6.y;
        a0 += f7.x; a1 += f7.y;
    }
    if (t + 8 <= c) {                               // one R14 8-edge body
        int i0 = row[t],   i1 = row[t+1], i2 = row[t+2], i3 = row[t+3];
        int i4 = row[t+4], i5 = row[t+5], i6 = row[t+6], i7 = row[t+7];
        unsigned j0 = (unsigned)(g ? i1 : i0);
        unsigned j1 = (unsigned)(g ? i3 : i2);
        unsigned j2 = (unsigned)(g ? i5 : i4);
        unsigned j3 = (unsigned)(g ? i7 : i6);
        unsigned u0 = xbu[j0 * 32u + cl];
        unsigned u1 = xbu[j1 * 32u + cl];
        unsigned u2 = xbu[j2 * 32u + cl];
        unsigned u3 = xbu[j3 * 32u + cl];
        float2 f0 = upk_f16(u0), f1 = upk_f16(u1), f2 = upk_f16(u2), f3 = upk_f16(u3);
        a0 += f0.x; a1 += f0.y;
        a0 += f1.x; a1 += f1.y;
        a0 += f2.x; a1 += f2.y;
        a0 += f3.x; a1 += f3.y;
        t += 8;
    }
    for (; t + 2 <= c; t += 2) {
        int i0 = row[t], i1 = row[t+1];
        unsigned j = (unsigned)(g ? i1 : i0);
        float2 f = upk_f16(xbu[j * 32u + cl]);
        a0 += f.x; a1 += f.y;
    }
    if (t < c && g == 0) {                          // odd leftover: group 0 only
        float2 f = upk_f16(xbu[(unsigned)row[t] * 32u + cl]);
        a0 += f.x; a1 += f.y;
    }
    a0 += __shfl_xor(a0, 32, 64);                   // cross-group reduce
    a1 += __shfl_xor(a1, 32, 64);
    float inv = (c > 0) ? 1.f / (float)c : 0.f;
    unsigned pk = pk_f16(a0 * inv, a1 * inv);
    if (g == 0) ((unsigned*)aggh)[(size_t)w * 32 + cl] = pk;
}

// ---------------- conv (MFMA, R21/R14 form, FROZEN): 64 nodes/block ----------------
__global__ __launch_bounds__(256) void conv_kernel(
    __half* __restrict__ xh, const __half* __restrict__ aggh,
    const float* __restrict__ W, const float* __restrict__ bias,
    const float* __restrict__ g, const float* __restrict__ beta)
{
    __shared__ __half Wt[64][136];    // Wt[col][k] = f16(W[k][col]); stride 136: 16B-aligned
    __shared__ float s_out[64][68];   // fp32 matmul result; stride 68: 16B-aligned

    int t = threadIdx.x;

    // ---- stage W^T as f16 into LDS (coalesced global reads) ----
    {
        int c  = t & 63;
        int kb = (t >> 6) * 32;                   // wave w covers k rows kb..kb+31
#pragma unroll
        for (int k = 0; k < 32; k += 2) {
            float w0 = W[(size_t)(kb + k)     * HF + c];
            float w1 = W[(size_t)(kb + k + 1) * HF + c];
            *(__half2*)&Wt[c][kb + k] = __float22half2_rn(float2{w0, w1});
        }
    }
    __syncthreads();

    // ---- per-wave 16x64 output tile via 16 MFMAs ----
    int l     = t & 63;
    int wv    = t >> 6;                           // wave 0..3 -> node rows wv*16..wv*16+15
    int arow16 = l & 15;                          // A-frag row within tile
    int ks    = (l >> 4) * 8;                     // A/B-frag k-slot base: 0,8,16,24
    int node  = blockIdx.x * 64 + wv * 16 + arow16;

    const __half* xrow = xh   + (size_t)node * HF;
    const __half* grow = aggh + (size_t)node * HF;
    f16x8 a0 = *(const f16x8*)(xrow + ks);        // k =   0+ks..   (x half, W rows 0..63)
    f16x8 a1 = *(const f16x8*)(xrow + 32 + ks);   // k =  32+ks..
    f16x8 a2 = *(const f16x8*)(grow + ks);        // k =  64+ks..   (agg half, W rows 64..127)
    f16x8 a3 = *(const f16x8*)(grow + 32 + ks);   // k =  96+ks..

    int orow = wv * 16 + (l >> 4) * 4;            // D rows this lane holds (reg j -> orow+j)
#pragma unroll
    for (int ct = 0; ct < 4; ++ct) {              // 4 column tiles of 16
        int col = (l & 15) + ct * 16;
        f16x8 b0 = *(const f16x8*)&Wt[col][ks];
        f16x8 b1 = *(const f16x8*)&Wt[col][32 + ks];
        f16x8 b2 = *(const f16x8*)&Wt[col][64 + ks];
        f16x8 b3 = *(const f16x8*)&Wt[col][96 + ks];
        f32x4 acc = {0.f, 0.f, 0.f, 0.f};
        acc = __builtin_amdgcn_mfma_f32_16x16x32_f16(a0, b0, acc, 0, 0, 0);
        acc = __builtin_amdgcn_mfma_f32_16x16x32_f16(a1, b1, acc, 0, 0, 0);
        acc = __builtin_amdgcn_mfma_f32_16x16x32_f16(a2, b2, acc, 0, 0, 0);
        acc = __builtin_amdgcn_mfma_f32_16x16x32_f16(a3, b3, acc, 0, 0, 0);
#pragma unroll
        for (int j = 0; j < 4; ++j)
            s_out[orow + j][col] = acc[j];
    }
    __syncthreads();

    // ---- epilogue: 4 threads/node, 16 ch each: +bias +residual, LN, relu, pack ----
    int nb = t >> 2;                              // node-in-block 0..63
    int q  = t & 3;                               // channel quarter
    int node2 = blockIdx.x * 64 + nb;
    const float* srow = &s_out[nb][q * 16];
    const float* b2   = bias + q * 16;
    float v[16];
#pragma unroll
    for (int i = 0; i < 16; ++i) v[i] = srow[i] + b2[i];

    const uint4* xr = (const uint4*)(xh + (size_t)node2 * HF + q * 16);
    uint4 r0 = xr[0], r1 = xr[1];
    {
        float2 f;
        f = upk_f16(r0.x); v[0] += f.x;  v[1] += f.y;
        f = upk_f16(r0.y); v[2] += f.x;  v[3] += f.y;
        f = upk_f16(r0.z); v[4] += f.x;  v[5] += f.y;
        f = upk_f16(r0.w); v[6] += f.x;  v[7] += f.y;
        f = upk_f16(r1.x); v[8] += f.x;  v[9] += f.y;
        f = upk_f16(r1.y); v[10] += f.x; v[11] += f.y;
        f = upk_f16(r1.z); v[12] += f.x; v[13] += f.y;
        f = upk_f16(r1.w); v[14] += f.x; v[15] += f.y;
    }
    float ps = 0.f, pq = 0.f;
#pragma unroll
    for (int i = 0; i < 16; ++i) { ps += v[i]; pq += v[i] * v[i]; }
    ps += __shfl_xor(ps, 1, 64); ps += __shfl_xor(ps, 2, 64);
    pq += __shfl_xor(pq, 1, 64); pq += __shfl_xor(pq, 2, 64);
    float mu  = ps * (1.f / HF);
    float var = pq * (1.f / HF) - mu * mu;
    float rs  = rsqrtf(var + LN_EPS);

    const float* g2  = g    + q * 16;
    const float* be2 = beta + q * 16;
    float y[16];
#pragma unroll
    for (int i = 0; i < 16; ++i)
        y[i] = fmaxf((v[i] - mu) * rs * g2[i] + be2[i], 0.f);

    uint4* hdst = (uint4*)(xh + (size_t)node2 * HF + q * 16);
    uint4 o0, o1;
    o0.x = pk_f16(y[0],  y[1]);  o0.y = pk_f16(y[2],  y[3]);
    o0.z = pk_f16(y[4],  y[5]);  o0.w = pk_f16(y[6],  y[7]);
    o1.x = pk_f16(y[8],  y[9]);  o1.y = pk_f16(y[10], y[11]);
    o1.z = pk_f16(y[12], y[13]); o1.w = pk_f16(y[14], y[15]);
    hdst[0] = o0; hdst[1] = o1;
}

// ---------------- output head: out = xh@out_w + out_b (2 threads/node, fp32 out) ----------------
__global__ __launch_bounds__(256) void out_kernel(const __half* __restrict__ xh,
                                                  const float* __restrict__ W,
                                                  const float* __restrict__ bias,
                                                  float* __restrict__ out)
{
    int lane = threadIdx.x & 63;
    int waveid = threadIdx.x >> 6;
    int half = __builtin_amdgcn_readfirstlane(waveid & 1);   // pin uniformity
    int nib = (waveid >> 1) * 64 + lane;
    int node = blockIdx.x * 128 + nib;
    const uint4* rp = (const uint4*)(xh + (size_t)node * HF);

    float o[16];
    const float* b2 = bias + half * 16;
#pragma unroll
    for (int j = 0; j < 16; ++j) o[j] = b2[j];

#pragma unroll 1
    for (int kc = 0; kc < HF; kc += 16) {
        uint4 u0 = rp[kc >> 3];
        uint4 u1 = rp[(kc >> 3) + 1];
        float av[16];
        float2 f;
        f = upk_f16(u0.x); av[0]=f.x;  av[1]=f.y;
        f = upk_f16(u0.y); av[2]=f.x;  av[3]=f.y;
        f = upk_f16(u0.z); av[4]=f.x;  av[5]=f.y;
        f = upk_f16(u0.w); av[6]=f.x;  av[7]=f.y;
        f = upk_f16(u1.x); av[8]=f.x;  av[9]=f.y;
        f = upk_f16(u1.y); av[10]=f.x; av[11]=f.y;
        f = upk_f16(u1.z); av[12]=f.x; av[13]=f.y;
        f = upk_f16(u1.w); av[14]=f.x; av[15]=f.y;
#pragma unroll
        for (int u = 0; u < 16; ++u) {
            const float* wr = W + (kc + u) * OUTF + half * 16;   // uniform -> s_load
#pragma unroll
            for (int j = 0; j < 16; ++j) o[j] = fmaf(av[u], wr[j], o[j]);
        }
    }

    float4* dst = (float4*)(out + (size_t)node * OUTF + half * 16);
#pragma unroll
    for (int q = 0; q < 4; ++q) {
        float4 v; v.x = o[4*q]; v.y = o[4*q+1]; v.z = o[4*q+2]; v.w = o[4*q+3];
        dst[q] = v;
    }
}

extern "C" void kernel_launch(void* const* d_in, const int* in_sizes, int n_in,
                              void* d_out, int out_size, void* d_ws, size_t ws_size,
                              hipStream_t stream)
{
    const float* nf     = (const float*)d_in[0];
    const int*   ei     = (const int*)  d_in[1];   // edge_indices (B,2,E)
    const float* enc_w1 = (const float*)d_in[3];
    const float* enc_b1 = (const float*)d_in[4];
    const float* enc_w2 = (const float*)d_in[5];
    const float* enc_b2 = (const float*)d_in[6];
    const float* conv_w = (const float*)d_in[7];   // (3,128,64)
    const float* conv_b = (const float*)d_in[8];   // (3,64)
    const float* ln_g   = (const float*)d_in[9];
    const float* ln_b   = (const float*)d_in[10];
    const float* out_w  = (const float*)d_in[11];  // (64,32)
    const float* out_b  = (const float*)d_in[12];

    // workspace (~53 MB); bkt aliases agh (bucket data dead once fill2 runs)
    char* w = (char*)d_ws;
    __half* xh   = (__half*)w;  w += (size_t)NODES * HF * 2;              // 20.5 MB
    __half* agh  = (__half*)w;  w += (size_t)NODES * HF * 2;              // 20.5 MB
    unsigned* bkt = (unsigned*)agh;   // 256 buckets * 16384 * 4B = 16.8 MB
    int* cnt     = (int*)w;     w += (size_t)NODES * sizeof(int);
    int* off     = (int*)w;     w += (size_t)NODES * sizeof(int);
    int* csr     = (int*)w;     w += (size_t)NB * NE * sizeof(int);       // 10.24 MB
    int* gcur    = (int*)w;                                               // 256 ints

    hipMemsetAsync(gcur, 0, 256 * sizeof(int), stream);

    enc_kernel<<<NODES / 256, 256, 0, stream>>>(nf, enc_w1, enc_b1, enc_w2, enc_b2, xh);
    bucket_kernel<<<NB * NCHUNK, 256, 0, stream>>>(ei, gcur, bkt);
    count2_kernel<<<NB * 16, 512, 0, stream>>>(bkt, gcur, cnt);
    scan_kernel<<<NB, 256, 0, stream>>>(cnt, off);
    fill2_kernel<<<NB * 16, 512, 0, stream>>>(bkt, gcur, off, csr);

    for (int l = 0; l < 3; ++l) {
        agg_kernel<<<NODES / 4, 256, 0, stream>>>(xh, cnt, off, csr, agh);
        conv_kernel<<<NODES / 64, 256, 0, stream>>>(xh, agh,
                                                    conv_w + (size_t)l * 2 * HF * HF,
                                                    conv_b + (size_t)l * HF,
                                                    ln_g + (size_t)l * HF,
                                                    ln_b + (size_t)l * HF);
    }
    out_kernel<<<NODES / 128, 256, 0, stream>>>(xh, out_w, out_b, (float*)d_out);
}